// Round 2
// baseline (386.564 us; speedup 1.0000x reference)
//
#include <hip/hip_runtime.h>
#include <stdint.h>
#include <stddef.h>

// AttentiveTransformer: B=65536, D_IN=128, F=512, fp32
#define NROWS 65536
#define DK 128
#define NF 512
#define BN_EPS 1e-3f

typedef __attribute__((ext_vector_type(8))) short short8;   // 8 x bf16
typedef __attribute__((ext_vector_type(4))) float f32x4;    // MFMA acc

__device__ __forceinline__ unsigned short f2bf(float f) {
  unsigned int u = __builtin_bit_cast(unsigned int, f);
  u += 0x7fffu + ((u >> 16) & 1u);     // RNE
  return (unsigned short)(u >> 16);
}
__device__ __forceinline__ float bf2f(unsigned short h) {
  unsigned int u = ((unsigned int)h) << 16;
  return __builtin_bit_cast(float, u);
}

// ---------------------------------------------------------------------------
// Prep: fold BN scale alpha into W, transpose to [512][128], split bf16 hi/lo.
// delta[f] = (b-mean)*alpha + beta  (used as MFMA accumulator init).
// ---------------------------------------------------------------------------
__global__ void prep_kernel(const float* __restrict__ W,
                            const float* __restrict__ bias,
                            const float* __restrict__ gamma,
                            const float* __restrict__ beta,
                            const float* __restrict__ mean,
                            const float* __restrict__ var,
                            unsigned short* __restrict__ wt_hi,
                            unsigned short* __restrict__ wt_lo,
                            float* __restrict__ delta) {
  int bid = blockIdx.x, tid = threadIdx.x;
  if (bid < 256) {
    int idx = bid * 256 + tid;        // over [128][512]
    int d = idx >> 9, f = idx & 511;
    float a = gamma[f] * rsqrtf(var[f] + BN_EPS);
    float wv = W[idx] * a;            // alpha folded into the weights
    unsigned short wh = f2bf(wv);
    wt_hi[(size_t)f * DK + d] = wh;
    wt_lo[(size_t)f * DK + d] = f2bf(wv - bf2f(wh));
  } else {
#pragma unroll
    for (int i = 0; i < 2; ++i) {
      int f = tid + i * 256;
      float a = gamma[f] * rsqrtf(var[f] + BN_EPS);
      delta[f] = (bias[f] - mean[f]) * a + beta[f];
    }
  }
}

// ---------------------------------------------------------------------------
// Fused, LDS-free: one wave = 16 batch rows x all 512 features in registers.
// MFMA operands SWAPPED vs the classic pattern: A = W fragment, B = inp
// fragment, so C/D maps  batch row = lane&15,  feature = quad*4+reg+16*t.
// Each lane then holds 128 features (32 x float4-contiguous) of ONE row:
//   - prior loads / out stores are coalesced float4
//   - sparsemax reduction needs only xor-16 and xor-32 shuffles
//   - no LDS, no __syncthreads: all phases overlap freely across waves
// ---------------------------------------------------------------------------
__global__ __launch_bounds__(256, 2) void fused_kernel(
    const float* __restrict__ inp,            // [65536][128]
    const float* __restrict__ prior,          // [65536][512]
    const unsigned short* __restrict__ wt_hi, // [512][128] bf16 hi (alpha-folded)
    const unsigned short* __restrict__ wt_lo, // [512][128] bf16 lo
    const float* __restrict__ delta,          // [512]
    float* __restrict__ out) {                // [65536][512]
  const int tid = threadIdx.x;
  const int l = tid & 63;
  const int q = l >> 4;          // quad 0..3
  const int li = l & 15;
  const int wvi = tid >> 6;      // wave 0..3
  const int row = blockIdx.x * 64 + wvi * 16 + li;   // this lane's batch row

  // ---- inp fragment (B operand): inp[row][kk*32 + q*8 + j], split hi/lo ----
  short8 bh[4], bl[4];
  const float* arow = inp + (size_t)row * DK + q * 8;
#pragma unroll
  for (int kk = 0; kk < 4; ++kk) {
    float4 v0 = *(const float4*)(arow + kk * 32);
    float4 v1 = *(const float4*)(arow + kk * 32 + 4);
    float av[8] = {v0.x, v0.y, v0.z, v0.w, v1.x, v1.y, v1.z, v1.w};
    short8 h, lo;
#pragma unroll
    for (int j = 0; j < 8; ++j) {
      unsigned short hb = f2bf(av[j]);
      h[j] = (short)hb;
      lo[j] = (short)f2bf(av[j] - bf2f(hb));
    }
    bh[kk] = h;
    bl[kk] = lo;
  }

  // ---- accumulators = z values; init with BN offset delta ----
  const size_t prow = (size_t)row * NF;
  f32x4 z[32];
#pragma unroll
  for (int t = 0; t < 32; ++t)
    z[t] = *(const f32x4*)(delta + t * 16 + q * 4);

  // ---- MFMA main loop over 32 feature tiles; prior folded in per tile ----
#pragma unroll
  for (int t = 0; t < 32; ++t) {
    const unsigned short* wh = wt_hi + (size_t)(t * 16 + li) * DK + q * 8;
    const unsigned short* wl = wt_lo + (size_t)(t * 16 + li) * DK + q * 8;
    f32x4 pv = *(const f32x4*)(prior + prow + t * 16 + q * 4);
#pragma unroll
    for (int kk = 0; kk < 4; ++kk) {
      short8 WH = *(const short8*)(wh + kk * 32);
      short8 WL = *(const short8*)(wl + kk * 32);
      z[t] = __builtin_amdgcn_mfma_f32_16x16x32_bf16(WH, bh[kk], z[t], 0, 0, 0);
      z[t] = __builtin_amdgcn_mfma_f32_16x16x32_bf16(WH, bl[kk], z[t], 0, 0, 0);
      z[t] = __builtin_amdgcn_mfma_f32_16x16x32_bf16(WL, bh[kk], z[t], 0, 0, 0);
    }
    z[t][0] *= pv[0];
    z[t][1] *= pv[1];
    z[t][2] *= pv[2];
    z[t][3] *= pv[3];
  }

  // ---- row max over 128 local + lanes {li, li+16, li+32, li+48} ----
  float mx = z[0][0];
#pragma unroll
  for (int t = 0; t < 32; ++t)
#pragma unroll
    for (int r = 0; r < 4; ++r) mx = fmaxf(mx, z[t][r]);
  mx = fmaxf(mx, __shfl_xor(mx, 16, 64));
  mx = fmaxf(mx, __shfl_xor(mx, 32, 64));

  // ---- Michelot fixed-point: tau <- (sum_S - 1)/|S|, S = {z > tau} ----
  float tau = mx - 1.0f;
  float cprev = -1.0f;
  for (int it = 0; it < 40; ++it) {
    float s = 0.0f, c = 0.0f;
#pragma unroll
    for (int t = 0; t < 32; ++t)
#pragma unroll
      for (int r = 0; r < 4; ++r) {
        bool in = z[t][r] > tau;
        s += in ? z[t][r] : 0.0f;
        c += in ? 1.0f : 0.0f;
      }
    s += __shfl_xor(s, 16, 64);
    s += __shfl_xor(s, 32, 64);
    c += __shfl_xor(c, 16, 64);
    c += __shfl_xor(c, 32, 64);
    tau = (s - 1.0f) / c;
    if (__all(c == cprev)) break;   // support fixed -> converged
    cprev = c;
  }

  // ---- write mask = max(z - tau, 0), coalesced float4 ----
  float* orow = out + prow;
#pragma unroll
  for (int t = 0; t < 32; ++t) {
    f32x4 ov;
#pragma unroll
    for (int r = 0; r < 4; ++r) ov[r] = fmaxf(z[t][r] - tau, 0.0f);
    *(f32x4*)(orow + t * 16 + q * 4) = ov;
  }
}

// ---------------------------------------------------------------------------
extern "C" void kernel_launch(void* const* d_in, const int* in_sizes, int n_in,
                              void* d_out, int out_size, void* d_ws, size_t ws_size,
                              hipStream_t stream) {
  const float* inp   = (const float*)d_in[0];   // [65536][128]
  const float* prior = (const float*)d_in[1];   // [65536][512]
  const float* W     = (const float*)d_in[2];   // [128][512]
  const float* bias  = (const float*)d_in[3];   // [512]
  const float* gamma = (const float*)d_in[4];
  const float* beta  = (const float*)d_in[5];
  const float* mean  = (const float*)d_in[6];
  const float* var   = (const float*)d_in[7];
  float* out = (float*)d_out;

  // workspace carve: 131072 + 131072 + 2048 bytes
  unsigned short* wt_hi = (unsigned short*)d_ws;
  unsigned short* wt_lo = wt_hi + (size_t)NF * DK;
  float* delta = (float*)(wt_lo + (size_t)NF * DK);

  prep_kernel<<<257, 256, 0, stream>>>(W, bias, gamma, beta, mean, var,
                                       wt_hi, wt_lo, delta);
  fused_kernel<<<NROWS / 64, 256, 0, stream>>>(inp, prior, wt_hi, wt_lo,
                                               delta, out);
}

// Round 3
// 354.519 us; speedup vs baseline: 1.0904x; 1.0904x over previous
//
#include <hip/hip_runtime.h>
#include <stdint.h>
#include <stddef.h>

// AttentiveTransformer: B=65536, D_IN=128, F=512, fp32
#define NROWS 65536
#define DK 128
#define NF 512
#define LDS_STRIDE 516          // 512 + 4 pad: breaks pow-2 bank aliasing
#define BN_EPS 1e-3f

typedef __attribute__((ext_vector_type(8))) short short8;   // 8 x bf16
typedef __attribute__((ext_vector_type(4))) float f32x4;

__device__ __forceinline__ unsigned short f2bf(float f) {
  unsigned int u = __builtin_bit_cast(unsigned int, f);
  u += 0x7fffu + ((u >> 16) & 1u);     // RNE
  return (unsigned short)(u >> 16);
}
__device__ __forceinline__ float bf2f(unsigned short h) {
  unsigned int u = ((unsigned int)h) << 16;
  return __builtin_bit_cast(float, u);
}

// ---------------------------------------------------------------------------
// Prep: fold BN scale alpha into W, transpose to [512][128], split bf16 hi/lo.
// delta[f] = (b-mean)*alpha + beta  (added in the epilogue).
// ---------------------------------------------------------------------------
__global__ void prep_kernel(const float* __restrict__ W,
                            const float* __restrict__ bias,
                            const float* __restrict__ gamma,
                            const float* __restrict__ beta,
                            const float* __restrict__ mean,
                            const float* __restrict__ var,
                            unsigned short* __restrict__ wt_hi,
                            unsigned short* __restrict__ wt_lo,
                            float* __restrict__ delta) {
  int bid = blockIdx.x, tid = threadIdx.x;
  if (bid < 256) {
    int idx = bid * 256 + tid;        // over [128][512]
    int d = idx >> 9, f = idx & 511;
    float a = gamma[f] * rsqrtf(var[f] + BN_EPS);
    float wv = W[idx] * a;            // alpha folded into weights
    unsigned short wh = f2bf(wv);
    wt_hi[(size_t)f * DK + d] = wh;
    wt_lo[(size_t)f * DK + d] = f2bf(wv - bf2f(wh));
  } else {
#pragma unroll
    for (int i = 0; i < 2; ++i) {
      int f = tid + i * 256;
      float a = gamma[f] * rsqrtf(var[f] + BN_EPS);
      delta[f] = (bias[f] - mean[f]) * a + beta[f];
    }
  }
}

// ---------------------------------------------------------------------------
// Fused kernel, 16 rows per block, 256 threads (4 waves).
//  Phase 1: wave w computes cols [128w, 128w+128) for all 16 rows via
//           split-bf16 MFMA (A=inp frag, B=W frag; verified R1 layout:
//           C/D col = n0+t*16+(l&15), row = (l>>4)*4+r). Epilogue adds
//           delta and writes z to padded LDS (stride 516 -> <=2-way banks).
//  Prior prefetch: 8 float4/lane issued BEFORE the barrier (acc regs dead
//           by then) so HBM latency overlaps the barrier drain.
//  Phase 2: 16-lane group owns one full row (coalesced float4 prior/out),
//           Michelot fixed-point sparsemax, 4-step xor-shuffle reductions.
// Resources: ~32 A-frag VGPR + 32 acc AGPR + ~32 prefetch -> ~120 total,
//           LDS 33 KB -> target 4 waves/SIMD, 4 blocks/CU (~50% occupancy).
// ---------------------------------------------------------------------------
__global__ __launch_bounds__(256, 4) void fused_kernel(
    const float* __restrict__ inp,            // [65536][128]
    const float* __restrict__ prior,          // [65536][512]
    const unsigned short* __restrict__ wt_hi, // [512][128] bf16 hi (alpha-folded)
    const unsigned short* __restrict__ wt_lo, // [512][128] bf16 lo
    const float* __restrict__ delta,          // [512]
    float* __restrict__ out) {                // [65536][512]
  __shared__ float zsh[16 * LDS_STRIDE];      // 33 KiB

  const int tid = threadIdx.x;
  const int w = tid >> 6;        // wave 0..3
  const int l = tid & 63;
  const int q = l >> 4;          // quad 0..3
  const int li = l & 15;
  const int r0 = blockIdx.x * 16;
  const int n0 = w * 128;

  // ---- Phase 1a: load + split-convert A fragments (16 rows) ----
  short8 ah[4], al[4];
  const float* arow = inp + (size_t)(r0 + li) * DK + q * 8;
#pragma unroll
  for (int kk = 0; kk < 4; ++kk) {
    float4 v0 = *(const float4*)(arow + kk * 32);
    float4 v1 = *(const float4*)(arow + kk * 32 + 4);
    float av[8] = {v0.x, v0.y, v0.z, v0.w, v1.x, v1.y, v1.z, v1.w};
    short8 h, lo;
#pragma unroll
    for (int j = 0; j < 8; ++j) {
      unsigned short hb = f2bf(av[j]);
      h[j] = (short)hb;
      lo[j] = (short)f2bf(av[j] - bf2f(hb));
    }
    ah[kk] = h;
    al[kk] = lo;
  }

  // ---- Phase 1b: MFMA, 3-product split-bf16 ----
  f32x4 acc[8];
#pragma unroll
  for (int t = 0; t < 8; ++t) acc[t] = (f32x4){0.f, 0.f, 0.f, 0.f};

#pragma unroll
  for (int t = 0; t < 8; ++t) {
    const unsigned short* wbh = wt_hi + (size_t)(n0 + t * 16 + li) * DK + q * 8;
    const unsigned short* wbl = wt_lo + (size_t)(n0 + t * 16 + li) * DK + q * 8;
#pragma unroll
    for (int kk = 0; kk < 4; ++kk) {
      short8 WH = *(const short8*)(wbh + kk * 32);
      short8 WL = *(const short8*)(wbl + kk * 32);
      acc[t] = __builtin_amdgcn_mfma_f32_16x16x32_bf16(ah[kk], WH, acc[t], 0, 0, 0);
      acc[t] = __builtin_amdgcn_mfma_f32_16x16x32_bf16(al[kk], WH, acc[t], 0, 0, 0);
      acc[t] = __builtin_amdgcn_mfma_f32_16x16x32_bf16(ah[kk], WL, acc[t], 0, 0, 0);
    }
  }

  // ---- Phase 1c: +delta, write z to padded LDS ----
#pragma unroll
  for (int t = 0; t < 8; ++t) {
    int col = n0 + t * 16 + li;
    float dv = delta[col];
#pragma unroll
    for (int r = 0; r < 4; ++r) {
      zsh[(q * 4 + r) * LDS_STRIDE + col] = acc[t][r] + dv;
    }
  }

  // ---- Prior prefetch (before barrier; overlaps barrier drain) ----
  const int trow = w * 4 + q;                 // 0..15, this group's row
  const size_t grow = (size_t)(r0 + trow);
  f32x4 pv[8];
  const float* prow = prior + grow * NF + li * 4;
#pragma unroll
  for (int j = 0; j < 8; ++j) pv[j] = *(const f32x4*)(prow + 64 * j);

  __syncthreads();

  // ---- Phase 2: per-row prior-scaled sparsemax (16-lane group = row) ----
  float z[32];
#pragma unroll
  for (int j = 0; j < 8; ++j) {
    f32x4 zv = *(const f32x4*)&zsh[trow * LDS_STRIDE + li * 4 + 64 * j];
#pragma unroll
    for (int r = 0; r < 4; ++r) z[4 * j + r] = zv[r] * pv[j][r];
  }

  float mx = z[0];
#pragma unroll
  for (int j = 1; j < 32; ++j) mx = fmaxf(mx, z[j]);
#pragma unroll
  for (int off = 1; off <= 8; off <<= 1) mx = fmaxf(mx, __shfl_xor(mx, off, 64));

  // Michelot fixed-point: tau <- (sum_S - 1)/|S|, S = {z > tau}
  float tau = mx - 1.0f;
  float cprev = -1.0f;
  for (int it = 0; it < 40; ++it) {
    float s = 0.0f, c = 0.0f;
#pragma unroll
    for (int j = 0; j < 32; ++j) {
      bool in = z[j] > tau;
      s += in ? z[j] : 0.0f;
      c += in ? 1.0f : 0.0f;
    }
#pragma unroll
    for (int off = 1; off <= 8; off <<= 1) {
      s += __shfl_xor(s, off, 64);
      c += __shfl_xor(c, off, 64);
    }
    tau = (s - 1.0f) / c;
    if (__all(c == cprev)) break;   // support fixed -> converged
    cprev = c;
  }

  float* orow = out + grow * NF + li * 4;
#pragma unroll
  for (int j = 0; j < 8; ++j) {
    f32x4 ov;
#pragma unroll
    for (int r = 0; r < 4; ++r) ov[r] = fmaxf(z[4 * j + r] - tau, 0.0f);
    *(f32x4*)(orow + 64 * j) = ov;
  }
}

// ---------------------------------------------------------------------------
extern "C" void kernel_launch(void* const* d_in, const int* in_sizes, int n_in,
                              void* d_out, int out_size, void* d_ws, size_t ws_size,
                              hipStream_t stream) {
  const float* inp   = (const float*)d_in[0];   // [65536][128]
  const float* prior = (const float*)d_in[1];   // [65536][512]
  const float* W     = (const float*)d_in[2];   // [128][512]
  const float* bias  = (const float*)d_in[3];   // [512]
  const float* gamma = (const float*)d_in[4];
  const float* beta  = (const float*)d_in[5];
  const float* mean  = (const float*)d_in[6];
  const float* var   = (const float*)d_in[7];
  float* out = (float*)d_out;

  // workspace carve: 131072 + 131072 + 2048 bytes
  unsigned short* wt_hi = (unsigned short*)d_ws;
  unsigned short* wt_lo = wt_hi + (size_t)NF * DK;
  float* delta = (float*)(wt_lo + (size_t)NF * DK);

  prep_kernel<<<257, 256, 0, stream>>>(W, bias, gamma, beta, mean, var,
                                       wt_hi, wt_lo, delta);
  fused_kernel<<<NROWS / 16, 256, 0, stream>>>(inp, prior, wt_hi, wt_lo,
                                               delta, out);
}

// Round 4
// 330.595 us; speedup vs baseline: 1.1693x; 1.0724x over previous
//
#include <hip/hip_runtime.h>
#include <stdint.h>
#include <stddef.h>

// AttentiveTransformer: B=65536, D_IN=128, F=512, fp32
#define NROWS 65536
#define DK 128
#define NF 512
#define LDS_H 524               // halves per LDS row: 524*2B=1048B=262 words == 6 mod 32
#define BN_EPS 1e-3f

typedef __attribute__((ext_vector_type(8))) short short8;     // 8 x bf16
typedef __attribute__((ext_vector_type(8))) _Float16 half8;   // 8 x fp16
typedef __attribute__((ext_vector_type(4))) float f32x4;

__device__ __forceinline__ unsigned short f2bf(float f) {
  unsigned int u = __builtin_bit_cast(unsigned int, f);
  u += 0x7fffu + ((u >> 16) & 1u);     // RNE
  return (unsigned short)(u >> 16);
}
__device__ __forceinline__ float bf2f(unsigned short h) {
  unsigned int u = ((unsigned int)h) << 16;
  return __builtin_bit_cast(float, u);
}

// ---------------------------------------------------------------------------
// Prep: fold BN scale alpha into W, transpose to [512][128], split bf16 hi/lo.
// Mapping: consecutive tid -> consecutive d (same f) => contiguous stores;
// the strided W loads are L2-friendly (each line re-hit by 32 f-groups).
// ---------------------------------------------------------------------------
__global__ void prep_kernel(const float* __restrict__ W,
                            const float* __restrict__ bias,
                            const float* __restrict__ gamma,
                            const float* __restrict__ beta,
                            const float* __restrict__ mean,
                            const float* __restrict__ var,
                            unsigned short* __restrict__ wt_hi,
                            unsigned short* __restrict__ wt_lo,
                            float* __restrict__ delta) {
  int bid = blockIdx.x, tid = threadIdx.x;
  if (bid < 256) {
    int idx = bid * 256 + tid;        // over [512][128]
    int f = idx >> 7, d = idx & 127;
    float a = gamma[f] * rsqrtf(var[f] + BN_EPS);
    float wv = W[(size_t)d * NF + f] * a;   // alpha folded into weights
    unsigned short wh = f2bf(wv);
    wt_hi[idx] = wh;                  // wt[f][d], contiguous in tid
    wt_lo[idx] = f2bf(wv - bf2f(wh));
  } else {
#pragma unroll
    for (int i = 0; i < 2; ++i) {
      int f = tid + i * 256;
      float a = gamma[f] * rsqrtf(var[f] + BN_EPS);
      delta[f] = (bias[f] - mean[f]) * a + beta[f];
    }
  }
}

// ---------------------------------------------------------------------------
// Fused kernel: 512 threads (8 waves), 32 rows per block.
//  Phase 1: wave w computes cols [64w, 64w+64) x 32 rows (2 m-tiles) via
//           split-bf16 MFMA (verified layout: A-frag inp[r0+m*16+li][q*8+j],
//           B-frag wt[col][k]; C/D col = li, row = q*4+reg). Per-wave weight
//           traffic 32 KB for 32 rows = 8 KB/row (R1-level amortization)
//           with acc only 2x4 f32x4 = 32 regs (fits 4 waves/SIMD).
//  z staged as fp16 in LDS (33.5 KB, stride 524 halves: both access phases
//           <=2-way bank aliased = free per m136).
//  Prior prefetch before the barrier overlaps the vmcnt drain.
//  Phase 2: 16-lane group owns one row; Michelot fixed-point sparsemax.
// Occupancy target: 2 blocks/CU (16 waves) = 50%.
// ---------------------------------------------------------------------------
__global__ __launch_bounds__(512, 4) void fused_kernel(
    const float* __restrict__ inp,            // [65536][128]
    const float* __restrict__ prior,          // [65536][512]
    const unsigned short* __restrict__ wt_hi, // [512][128] bf16 hi (alpha-folded)
    const unsigned short* __restrict__ wt_lo, // [512][128] bf16 lo
    const float* __restrict__ delta,          // [512]
    float* __restrict__ out) {                // [65536][512]
  __shared__ _Float16 zsh[32 * LDS_H];        // 33536 B

  const int tid = threadIdx.x;
  const int w = tid >> 6;        // wave 0..7
  const int l = tid & 63;
  const int q = l >> 4;          // quad 0..3
  const int li = l & 15;
  const int r0 = blockIdx.x * 32;
  const int n0 = w * 64;         // this wave's column slice

  // ---- Phase 1a: load + split-convert A fragments (2 m-tiles, 32 rows) ----
  short8 ah[2][4], al[2][4];
#pragma unroll
  for (int m = 0; m < 2; ++m) {
    const float* arow = inp + (size_t)(r0 + m * 16 + li) * DK + q * 8;
#pragma unroll
    for (int kk = 0; kk < 4; ++kk) {
      float4 v0 = *(const float4*)(arow + kk * 32);
      float4 v1 = *(const float4*)(arow + kk * 32 + 4);
      float av[8] = {v0.x, v0.y, v0.z, v0.w, v1.x, v1.y, v1.z, v1.w};
      short8 h, lo;
#pragma unroll
      for (int j = 0; j < 8; ++j) {
        unsigned short hb = f2bf(av[j]);
        h[j] = (short)hb;
        lo[j] = (short)f2bf(av[j] - bf2f(hb));
      }
      ah[m][kk] = h;
      al[m][kk] = lo;
    }
  }

  // ---- Phase 1b: MFMA, 3-product split-bf16, 4 col-tiles ----
  f32x4 acc[2][4];
#pragma unroll
  for (int m = 0; m < 2; ++m)
#pragma unroll
    for (int t = 0; t < 4; ++t) acc[m][t] = (f32x4){0.f, 0.f, 0.f, 0.f};

#pragma unroll
  for (int t = 0; t < 4; ++t) {
    const unsigned short* wbh = wt_hi + (size_t)(n0 + t * 16 + li) * DK + q * 8;
    const unsigned short* wbl = wt_lo + (size_t)(n0 + t * 16 + li) * DK + q * 8;
#pragma unroll
    for (int kk = 0; kk < 4; ++kk) {
      short8 WH = *(const short8*)(wbh + kk * 32);
      short8 WL = *(const short8*)(wbl + kk * 32);
#pragma unroll
      for (int m = 0; m < 2; ++m) {
        acc[m][t] = __builtin_amdgcn_mfma_f32_16x16x32_bf16(ah[m][kk], WH, acc[m][t], 0, 0, 0);
        acc[m][t] = __builtin_amdgcn_mfma_f32_16x16x32_bf16(al[m][kk], WH, acc[m][t], 0, 0, 0);
        acc[m][t] = __builtin_amdgcn_mfma_f32_16x16x32_bf16(ah[m][kk], WL, acc[m][t], 0, 0, 0);
      }
    }
  }

  // ---- Phase 1c: +delta, fp16 convert, write z to LDS ----
#pragma unroll
  for (int t = 0; t < 4; ++t) {
    int col = n0 + t * 16 + li;
    float dv = delta[col];
#pragma unroll
    for (int m = 0; m < 2; ++m) {
#pragma unroll
      for (int r = 0; r < 4; ++r) {
        zsh[(m * 16 + q * 4 + r) * LDS_H + col] = (_Float16)(acc[m][t][r] + dv);
      }
    }
  }

  // ---- Prior prefetch (before barrier; overlaps the vmcnt drain) ----
  const int g = tid >> 4;                     // 0..31: this group's row
  const int li2 = tid & 15;
  const size_t grow = (size_t)(r0 + g);
  const float* prow = prior + grow * NF + li2 * 8;   // 8-float chunks per lane
  f32x4 pv[8];
#pragma unroll
  for (int j = 0; j < 4; ++j) {
    pv[2 * j]     = *(const f32x4*)(prow + 128 * j);
    pv[2 * j + 1] = *(const f32x4*)(prow + 128 * j + 4);
  }

  __syncthreads();

  // ---- Phase 2: per-row prior-scaled sparsemax (16-lane group = row) ----
  // lane's cols: li2*8 + 128*j + c, j=0..3, c=0..7
  float z[32];
#pragma unroll
  for (int j = 0; j < 4; ++j) {
    half8 hv = *(const half8*)&zsh[g * LDS_H + li2 * 8 + 128 * j];
#pragma unroll
    for (int c = 0; c < 8; ++c) {
      z[8 * j + c] = (float)hv[c] * pv[2 * j + (c >> 2)][c & 3];
    }
  }

  float mx = z[0];
#pragma unroll
  for (int j = 1; j < 32; ++j) mx = fmaxf(mx, z[j]);
#pragma unroll
  for (int off = 1; off <= 8; off <<= 1) mx = fmaxf(mx, __shfl_xor(mx, off, 64));

  // Michelot fixed-point: tau <- (sum_S - 1)/|S|, S = {z > tau};
  // support grows monotonically, c==cprev <=> converged.
  float tau = mx - 1.0f;
  float cprev = -1.0f;
  for (int it = 0; it < 40; ++it) {
    float s = 0.0f, c = 0.0f;
#pragma unroll
    for (int j = 0; j < 32; ++j) {
      bool in = z[j] > tau;
      s += in ? z[j] : 0.0f;
      c += in ? 1.0f : 0.0f;
    }
#pragma unroll
    for (int off = 1; off <= 8; off <<= 1) {
      s += __shfl_xor(s, off, 64);
      c += __shfl_xor(c, off, 64);
    }
    tau = (s - 1.0f) / c;
    if (__all(c == cprev)) break;
    cprev = c;
  }

  float* orow = out + grow * NF + li2 * 8;
#pragma unroll
  for (int j = 0; j < 4; ++j) {
    f32x4 ov0, ov1;
#pragma unroll
    for (int r = 0; r < 4; ++r) {
      ov0[r] = fmaxf(z[8 * j + r] - tau, 0.0f);
      ov1[r] = fmaxf(z[8 * j + 4 + r] - tau, 0.0f);
    }
    *(f32x4*)(orow + 128 * j) = ov0;
    *(f32x4*)(orow + 128 * j + 4) = ov1;
  }
}

// ---------------------------------------------------------------------------
extern "C" void kernel_launch(void* const* d_in, const int* in_sizes, int n_in,
                              void* d_out, int out_size, void* d_ws, size_t ws_size,
                              hipStream_t stream) {
  const float* inp   = (const float*)d_in[0];   // [65536][128]
  const float* prior = (const float*)d_in[1];   // [65536][512]
  const float* W     = (const float*)d_in[2];   // [128][512]
  const float* bias  = (const float*)d_in[3];   // [512]
  const float* gamma = (const float*)d_in[4];
  const float* beta  = (const float*)d_in[5];
  const float* mean  = (const float*)d_in[6];
  const float* var   = (const float*)d_in[7];
  float* out = (float*)d_out;

  // workspace carve: 131072 + 131072 + 2048 bytes
  unsigned short* wt_hi = (unsigned short*)d_ws;
  unsigned short* wt_lo = wt_hi + (size_t)NF * DK;
  float* delta = (float*)(wt_lo + (size_t)NF * DK);

  prep_kernel<<<257, 256, 0, stream>>>(W, bias, gamma, beta, mean, var,
                                       wt_hi, wt_lo, delta);
  fused_kernel<<<NROWS / 32, 512, 0, stream>>>(inp, prior, wt_hi, wt_lo,
                                               delta, out);
}